// Round 15
// baseline (157.367 us; speedup 1.0000x reference)
//
#include <hip/hip_runtime.h>
#include <hip/hip_bf16.h>
#include <math.h>

#define B_    4
#define H_    48
#define W_    48
#define N_    2304
#define C_    512
#define NH_   8
#define HD_   64
#define LKV_  684
#define LKP_  704      // padded kv length (11 * 64)

typedef __attribute__((ext_vector_type(8))) short short8;
typedef __attribute__((ext_vector_type(8))) unsigned short ushort8;
typedef __attribute__((ext_vector_type(4))) float f32x4;

#define MFMA16(a, b, c) __builtin_amdgcn_mfma_f32_16x16x32_bf16(a, b, c, 0, 0, 0)

__device__ __forceinline__ unsigned short f2bf(float f) {
  __hip_bfloat16 h = __float2bfloat16(f);
  return *reinterpret_cast<unsigned short*>(&h);
}
__device__ __forceinline__ float bf2f(unsigned short u) {
  unsigned int x = ((unsigned int)u) << 16;
  return *reinterpret_cast<float*>(&x);
}
__device__ __forceinline__ unsigned int cvtpk(float lo, float hi) {
  unsigned int r;
  asm("v_cvt_pk_bf16_f32 %0, %1, %2" : "=v"(r) : "v"(lo), "v"(hi));
  return r;
}
__device__ __forceinline__ float fexp2(float x) {   // raw v_exp_f32: 2^x
  float r;
  asm("v_exp_f32 %0, %1" : "=v"(r) : "v"(x));
  return r;
}
__device__ __forceinline__ void gld16(const unsigned short* g, unsigned short* l) {
  __builtin_amdgcn_global_load_lds(
      (const __attribute__((address_space(1))) void*)g,
      (__attribute__((address_space(3))) void*)l, 16, 0, 0);
}

#define SORTB 288    // argsort blocks (first in grid: long-pole overlap)
#define PACKB 1472   // 6,029,312 floats / (256 thr * 16 floats)

// ---------------- fused: both argsorts (blocks 0..287) + bf16 pack of
// 5 weights + x at 16 floats/thread (blocks 288..1759)
__global__ __launch_bounds__(256) void pack_sort(
    const float* __restrict__ lepe_w, const float* __restrict__ q_w,
    const float* __restrict__ kv1_w, const float* __restrict__ kv2_w,
    const float* __restrict__ proj_w, const float* __restrict__ x,
    unsigned short* __restrict__ wb, unsigned short* __restrict__ xb,
    const float* __restrict__ m1, const float* __restrict__ m2,
    int* __restrict__ i1, int* __restrict__ i2)
{
  __shared__ float key[N_];
  if (blockIdx.x >= SORTB) {
    int i = ((blockIdx.x - SORTB) * 256 + threadIdx.x) * 16;
    const float* s; unsigned short* d; int rel;
    if      (i < 262144)  { s = lepe_w; d = wb;           rel = i; }
    else if (i < 524288)  { s = q_w;    d = wb + 262144;  rel = i - 262144; }
    else if (i < 786432)  { s = kv1_w;  d = wb + 524288;  rel = i - 524288; }
    else if (i < 1048576) { s = kv2_w;  d = wb + 786432;  rel = i - 786432; }
    else if (i < 1310720) { s = proj_w; d = wb + 1048576; rel = i - 1048576; }
    else                  { s = x;      d = xb;           rel = i - 1310720; }
    const float4* sp = (const float4*)(s + rel);
    float4 v0 = sp[0], v1 = sp[1], v2 = sp[2], v3 = sp[3];
    ushort8 o0, o1;
    o0[0] = f2bf(v0.x); o0[1] = f2bf(v0.y); o0[2] = f2bf(v0.z); o0[3] = f2bf(v0.w);
    o0[4] = f2bf(v1.x); o0[5] = f2bf(v1.y); o0[6] = f2bf(v1.z); o0[7] = f2bf(v1.w);
    o1[0] = f2bf(v2.x); o1[1] = f2bf(v2.y); o1[2] = f2bf(v2.z); o1[3] = f2bf(v2.w);
    o1[4] = f2bf(v3.x); o1[5] = f2bf(v3.y); o1[6] = f2bf(v3.z); o1[7] = f2bf(v3.w);
    *(ushort8*)(d + rel)     = o0;
    *(ushort8*)(d + rel + 8) = o1;
    return;
  }
  const int blk = blockIdx.x;
  const int row = blk / 36, chunk = blk % 36;
  const float* m = (row < 4) ? (m1 + (size_t)row * N_) : (m2 + (size_t)(row - 4) * N_);
  int* out = (row < 4) ? (i1 + (size_t)row * N_) : (i2 + (size_t)(row - 4) * N_);
  for (int i = threadIdx.x; i < N_ / 4; i += 256)
    ((float4*)key)[i] = ((const float4*)m)[i];
  __syncthreads();
  const int e = chunk * 64 + (threadIdx.x >> 2);
  const int sl = threadIdx.x & 3;
  const float ki = key[e];
  int rank = 0;
  #pragma unroll 4
  for (int t = 0; t < N_ / 16; ++t) {
    int jb = sl * 4 + t * 16;
    float4 kv = *(const float4*)&key[jb];
    rank += (kv.x < ki) || (kv.x == ki && jb     < e);
    rank += (kv.y < ki) || (kv.y == ki && jb + 1 < e);
    rank += (kv.z < ki) || (kv.z == ki && jb + 2 < e);
    rank += (kv.w < ki) || (kv.w == ki && jb + 3 < e);
  }
  rank += __shfl_xor(rank, 1);
  rank += __shfl_xor(rank, 2);
  if (sl == 0) out[rank] = e;
}

// ---------------- shared bf16 MFMA GEMM body (NT), global_load_lds staging
struct GCfg {
  const unsigned short *A, *Bw;
  const float *bias;
  void *out;
  float sc;
  int bf;
  int nx;
};

__device__ __forceinline__ void gemm_body(
    const GCfg g, int id, unsigned short* Abuf, unsigned short* Bbuf)
{
  const int bx = id % g.nx, by = id / g.nx;
  const int tid = threadIdx.x;
  const int l = tid & 63, w = tid >> 6;
  const int wm = w >> 1, wn = w & 1;
  const int lo16 = l & 15, hi = l >> 4;
  const int row0 = bx * 128, col0 = by * 128;
  const int srow = tid >> 2, scol = (tid & 3) * 8;

  const unsigned short* Asrc = g.A + (size_t)(row0 + srow) * C_ + scol;
  const unsigned short* Bsrc = g.Bw + (size_t)(col0 + srow) * C_ + scol;

  f32x4 acc[4][4];
  #pragma unroll
  for (int m = 0; m < 4; ++m)
    #pragma unroll
    for (int n = 0; n < 4; ++n)
      #pragma unroll
      for (int r = 0; r < 4; ++r) acc[m][n][r] = 0.f;

  for (int k0 = 0; k0 < C_; k0 += 32) {
    __syncthreads();
    gld16(Asrc + k0,                    &Abuf[tid * 8]);
    gld16(Asrc + (size_t)64 * C_ + k0,  &Abuf[2048 + tid * 8]);
    gld16(Bsrc + k0,                    &Bbuf[tid * 8]);
    gld16(Bsrc + (size_t)64 * C_ + k0,  &Bbuf[2048 + tid * 8]);
    __syncthreads();
    short8 af[4], bf[4];
    #pragma unroll
    for (int m = 0; m < 4; ++m)
      af[m] = *(const short8*)&Abuf[(wm * 64 + m * 16 + lo16) * 32 + hi * 8];
    #pragma unroll
    for (int n = 0; n < 4; ++n)
      bf[n] = *(const short8*)&Bbuf[(wn * 64 + n * 16 + lo16) * 32 + hi * 8];
    #pragma unroll
    for (int m = 0; m < 4; ++m)
      #pragma unroll
      for (int n = 0; n < 4; ++n)
        acc[m][n] = MFMA16(af[m], bf[n], acc[m][n]);
  }

  #pragma unroll
  for (int m = 0; m < 4; ++m) {
    #pragma unroll
    for (int n = 0; n < 4; ++n) {
      int gcol = col0 + wn * 64 + n * 16 + lo16;
      #pragma unroll
      for (int r = 0; r < 4; ++r) {
        int grow = row0 + wm * 64 + m * 16 + hi * 4 + r;
        float v = acc[m][n][r] + g.bias[gcol];
        if (g.bf)
          ((unsigned short*)g.out)[(size_t)grow * C_ + gcol] = f2bf(v * g.sc);
        else
          ((float*)g.out)[(size_t)grow * C_ + gcol] = v;
      }
    }
  }
}

// ---------------- merged: lepe GEMM (0..287) + q GEMM (288..575) + pool (576..)
__global__ __launch_bounds__(256) void pool_gemm(
    GCfg g0, GCfg g1,
    const float* __restrict__ ctx,
    const int* __restrict__ idx1, const int* __restrict__ idx2,
    const float* __restrict__ f1w, const float* __restrict__ f1b,
    const float* __restrict__ f2w, const float* __restrict__ f2b_,
    unsigned short* __restrict__ seqb1, unsigned short* __restrict__ seqb2)
{
  __shared__ unsigned short Abuf[128 * 32];
  __shared__ unsigned short Bbuf[128 * 32];
  int bl = blockIdx.x;
  if (bl < 288) { gemm_body(g0, bl, Abuf, Bbuf); return; }
  if (bl < 576) { gemm_body(g1, bl - 288, Abuf, Bbuf); return; }
  bl -= 576;
  const int transposed = bl >= B_ * LKP_;
  if (transposed) bl -= B_ * LKP_;
  const int* idx = transposed ? idx2 : idx1;
  unsigned short* seqb = transposed ? seqb2 : seqb1;
  int b = bl / LKP_, l = bl % LKP_;
  unsigned short* dst = seqb + ((size_t)b * LKP_ + l) * C_;
  int c0 = threadIdx.x, c1 = threadIdx.x + 256;
  if (l >= LKV_) { dst[c0] = 0; dst[c1] = 0; return; }
  const int* id = idx + (size_t)b * N_;
  int j0, cnt;
  const float* fw; float fb;
  if (l < 12)       { j0 = l * 48;              cnt = 48; fw = f1w; fb = f1b[0]; }
  else if (l < 108) { j0 = 576 + (l - 12) * 12; cnt = 12; fw = f2w; fb = f2b_[0]; }
  else              { j0 = 1728 + (l - 108);    cnt = 1;  fw = nullptr; fb = 0.f; }
  const float* cb = ctx + (size_t)b * N_ * C_;
  float a0 = fb, a1 = fb;
  int r = 0;
  for (; r + 4 <= cnt; r += 4) {
    int4 nv = *(const int4*)(id + j0 + r);
    int n0 = nv.x, n1 = nv.y, n2 = nv.z, n3 = nv.w;
    if (transposed) {
      n0 = (n0 % 48) * 48 + n0 / 48; n1 = (n1 % 48) * 48 + n1 / 48;
      n2 = (n2 % 48) * 48 + n2 / 48; n3 = (n3 % 48) * 48 + n3 / 48;
    }
    const float* s0 = cb + (size_t)n0 * C_;
    const float* s1 = cb + (size_t)n1 * C_;
    const float* s2 = cb + (size_t)n2 * C_;
    const float* s3 = cb + (size_t)n3 * C_;
    float w0 = fw[r], w1 = fw[r+1], w2 = fw[r+2], w3 = fw[r+3];
    a0 += w0 * s0[c0] + w1 * s1[c0] + w2 * s2[c0] + w3 * s3[c0];
    a1 += w0 * s0[c1] + w1 * s1[c1] + w2 * s2[c1] + w3 * s3[c1];
  }
  for (; r < cnt; ++r) {
    int n = id[j0 + r];
    if (transposed) n = (n % 48) * 48 + n / 48;
    const float* src = cb + (size_t)n * C_;
    float wr = fw ? fw[r] : 1.f;
    a0 += wr * src[c0];
    a1 += wr * src[c1];
  }
  dst[c0] = f2bf(a0);
  dst[c1] = f2bf(a1);
}

// ---------------- merged: kv1 GEMM (0..87) + kv2 GEMM (88..175) + dwconv (176..)
__global__ __launch_bounds__(256) void gconv(
    GCfg g0, GCfg g1,
    const unsigned short* __restrict__ lin, const float* __restrict__ cw,
    const float* __restrict__ cb, unsigned short* __restrict__ outp)
{
  __shared__ unsigned short Abuf[128 * 32];
  __shared__ unsigned short Bbuf[128 * 32];
  const int tid = threadIdx.x;
  if (blockIdx.x < 88)  { gemm_body(g0, blockIdx.x, Abuf, Bbuf); return; }
  if (blockIdx.x < 176) { gemm_body(g1, blockIdx.x - 88, Abuf, Bbuf); return; }
  // ---- dwconv
  const int cg = tid & 63;
  const int wslot = (blockIdx.x - 176) * 4 + (tid >> 6);
  const int nslots = (gridDim.x - 176) * 4;

  float wf[72];
  const float* wsrc = cw + cg * 72;
  #pragma unroll
  for (int i = 0; i < 18; ++i)
    *(float4*)&wf[i * 4] = *(const float4*)(wsrc + i * 4);
  float bias[8];
  *(float4*)&bias[0] = *(const float4*)(cb + cg * 8);
  *(float4*)&bias[4] = *(const float4*)(cb + cg * 8 + 4);

  for (int pos = wslot; pos < B_ * N_; pos += nslots) {
    int wv = pos % W_;
    int r  = pos / W_;
    int hv = r % H_;
    int b  = r / H_;
    float acc[8];
    #pragma unroll
    for (int j = 0; j < 8; ++j) acc[j] = bias[j];
    #pragma unroll
    for (int dy = 0; dy < 3; ++dy) {
      int hh = hv + dy - 1;
      if (hh < 0 || hh >= H_) continue;
      #pragma unroll
      for (int dx = 0; dx < 3; ++dx) {
        int ww = wv + dx - 1;
        if (ww < 0 || ww >= W_) continue;
        ushort8 v = *(const ushort8*)(lin + ((((size_t)b * H_ + hh) * W_ + ww) * 64 + cg) * 8);
        #pragma unroll
        for (int j = 0; j < 8; ++j)
          acc[j] += wf[j * 9 + dy * 3 + dx] * bf2f(v[j]);
      }
    }
    ushort8 ov;
    #pragma unroll
    for (int j = 0; j < 8; ++j) ov[j] = f2bf(acc[j]);
    *(ushort8*)(outp + ((size_t)pos * 64 + cg) * 8) = ov;
  }
}

// ---------------- kv -> MFMA fragment-major K and V buffers
// Kf/Vf: [(bh*11 + t)*8 + frag*2 + s][lane][8] shorts, lane = lo16 + 16*hi.
__global__ __launch_bounds__(256) void kvpack(
    const unsigned short* __restrict__ kv1, const unsigned short* __restrict__ kv2,
    unsigned short* __restrict__ Kf, unsigned short* __restrict__ Vf)
{
  __shared__ unsigned short Vt[64][72];
  const int bh = blockIdx.x / 11, t = blockIdx.x % 11;
  const int h = bh & 7, b = bh >> 3;
  const unsigned short* src = (h < 4) ? kv1 : kv2;
  const int hcol = (h & 3) * 64;
  const int tid = threadIdx.x;

  #pragma unroll
  for (int pass = 0; pass < 2; ++pass) {
    int r = pass * 32 + (tid >> 3);
    int cc = (tid & 7) * 8;
    int l = t * 64 + r;
    uint4 v = make_uint4(0, 0, 0, 0);
    if (l < LKV_)
      v = *(const uint4*)&src[(size_t)(b * LKP_ + l) * C_ + 256 + hcol + cc];
    *(uint4*)&Vt[r][cc] = v;
  }
  __syncthreads();

  #pragma unroll
  for (int pass = 0; pass < 2; ++pass) {
    int o = pass * 256 + tid;
    int lane = o & 63, ns = o >> 6;
    int frag = ns >> 1, s = ns & 1;
    int lo16 = lane & 15, hi8 = (lane >> 4) * 8;
    size_t oidx = ((size_t)blockIdx.x * 8 + ns) * 512 + lane * 8;
    {
      int l = t * 64 + frag * 16 + lo16;
      uint4 val = make_uint4(0, 0, 0, 0);
      if (l < LKV_)
        val = *(const uint4*)&src[(size_t)(b * LKP_ + l) * C_ + hcol + s * 32 + hi8];
      *(uint4*)&Kf[oidx] = val;
    }
    {
      unsigned short tmp[8];
      #pragma unroll
      for (int j = 0; j < 8; ++j)
        tmp[j] = Vt[s * 32 + hi8 + j][frag * 16 + lo16];
      *(uint4*)&Vf[oidx] = *(uint4*)tmp;
    }
  }
}

// ---------------- fused flash attention: 16 q-rows/wave, 4 waves/block,
// swapped QK^T, FIXED-max softmax (M=0, raw v_exp_f32 — scores |s|<~2 so
// exp2(s) can't overflow; softmax renormalizes), cvt_pk P-pack, bf16 lepe
// epilogue.
__global__ __launch_bounds__(256) void attn_kernel(
    const unsigned short* __restrict__ Qb, const unsigned short* __restrict__ Kf,
    const unsigned short* __restrict__ Vf, const unsigned short* __restrict__ lepe,
    unsigned short* __restrict__ outb)
{
  __shared__ unsigned short P[4][16][72];
  const int tid = threadIdx.x;
  const int l = tid & 63, wv = tid >> 6;
  const int lo16 = l & 15, hi = l >> 4;
  const int qt64 = blockIdx.x % (N_ / 64);
  const int bh = blockIdx.x / (N_ / 64);
  const int h = bh & 7, b = bh >> 3;
  const int qrow0 = qt64 * 64 + wv * 16;

  const unsigned short* qptr = Qb + ((size_t)b * N_ + qrow0 + lo16) * C_ + h * 64;
  short8 qf0 = *(const short8*)(qptr + hi * 8);
  short8 qf1 = *(const short8*)(qptr + 32 + hi * 8);

  const unsigned short* kbase = Kf + (size_t)bh * 11 * 4096 + (size_t)l * 8;
  const unsigned short* vbase = Vf + (size_t)bh * 11 * 4096 + (size_t)l * 8;

  float lsum = 0.f;
  f32x4 o[4];
  #pragma unroll
  for (int df = 0; df < 4; ++df)
    #pragma unroll
    for (int r = 0; r < 4; ++r) o[df][r] = 0.f;

  short8 ka0[4], ka1[4], kn0[4], kn1[4];
  #pragma unroll
  for (int n = 0; n < 4; ++n) {
    ka0[n] = *(const short8*)(kbase + (size_t)(n * 2 + 0) * 512);
    ka1[n] = *(const short8*)(kbase + (size_t)(n * 2 + 1) * 512);
  }

  for (int t = 0; t < 11; ++t) {
    short8 vf0[4], vf1[4];
    #pragma unroll
    for (int i = 0; i < 4; ++i) {
      vf0[i] = *(const short8*)(vbase + (size_t)(t * 8 + i * 2 + 0) * 512);
      vf1[i] = *(const short8*)(vbase + (size_t)(t * 8 + i * 2 + 1) * 512);
    }
    if (t < 10) {
      #pragma unroll
      for (int n = 0; n < 4; ++n) {
        kn0[n] = *(const short8*)(kbase + (size_t)((t + 1) * 8 + n * 2 + 0) * 512);
        kn1[n] = *(const short8*)(kbase + (size_t)((t + 1) * 8 + n * 2 + 1) * 512);
      }
    }
    const f32x4 z = {0.f, 0.f, 0.f, 0.f};
    f32x4 s[4];
    #pragma unroll
    for (int n = 0; n < 4; ++n) {
      s[n] = MFMA16(ka0[n], qf0, z);
      s[n] = MFMA16(ka1[n], qf1, s[n]);
    }
    if (t == 10) {
      #pragma unroll
      for (int n = 0; n < 4; ++n)
        #pragma unroll
        for (int r = 0; r < 4; ++r)
          if (n * 16 + hi * 4 + r >= LKV_ - 640) s[n][r] = -1e30f;
    }
    // fixed-max exp2 (M=0): purely per-lane, 1 transcendental per score
    float psl = 0.f;
    #pragma unroll
    for (int n = 0; n < 4; ++n) {
      #pragma unroll
      for (int rp = 0; rp < 2; ++rp) {
        float e0 = fexp2(s[n][2 * rp]);
        float e1 = fexp2(s[n][2 * rp + 1]);
        psl += e0 + e1;
        *(unsigned int*)&P[wv][lo16][n * 16 + hi * 4 + 2 * rp] = cvtpk(e0, e1);
      }
    }
    lsum += psl;
    short8 pa0 = *(const short8*)&P[wv][lo16][hi * 8];
    short8 pa1 = *(const short8*)&P[wv][lo16][32 + hi * 8];
    #pragma unroll
    for (int df = 0; df < 4; ++df) {
      o[df] = MFMA16(pa0, vf0[df], o[df]);
      o[df] = MFMA16(pa1, vf1[df], o[df]);
    }
    #pragma unroll
    for (int n = 0; n < 4; ++n) { ka0[n] = kn0[n]; ka1[n] = kn1[n]; }
  }

  lsum += __shfl_xor(lsum, 16);
  lsum += __shfl_xor(lsum, 32);
  float rr[4];
  #pragma unroll
  for (int r = 0; r < 4; ++r) rr[r] = 1.f / __shfl(lsum, hi * 4 + r);
  #pragma unroll
  for (int df = 0; df < 4; ++df)
    #pragma unroll
    for (int r = 0; r < 4; ++r) {
      size_t off = ((size_t)b * N_ + qrow0 + hi * 4 + r) * C_ + h * 64 + df * 16 + lo16;
      outb[off] = f2bf(o[df][r] * rr[r] + bf2f(lepe[off]));
    }
}

// ---------------- single-config GEMM (final projection)
__global__ __launch_bounds__(256) void gemm1(GCfg g)
{
  __shared__ unsigned short Abuf[128 * 32];
  __shared__ unsigned short Bbuf[128 * 32];
  gemm_body(g, blockIdx.x, Abuf, Bbuf);
}

extern "C" void kernel_launch(void* const* d_in, const int* in_sizes, int n_in,
                              void* d_out, int out_size, void* d_ws, size_t ws_size,
                              hipStream_t stream)
{
  const float* x      = (const float*)d_in[0];
  const float* ctx    = (const float*)d_in[1];
  const float* mask1  = (const float*)d_in[2];
  const float* mask2  = (const float*)d_in[3];
  const float* q_w    = (const float*)d_in[4];
  const float* q_b    = (const float*)d_in[5];
  const float* kv1_w  = (const float*)d_in[6];
  const float* kv1_b  = (const float*)d_in[7];
  const float* kv2_w  = (const float*)d_in[8];
  const float* kv2_b  = (const float*)d_in[9];
  const float* f1_w   = (const float*)d_in[10];
  const float* f1_b   = (const float*)d_in[11];
  const float* f2_w   = (const float*)d_in[12];
  const float* f2_b   = (const float*)d_in[13];
  const float* lepe_w = (const float*)d_in[14];
  const float* lepe_b = (const float*)d_in[15];
  const float* lcw    = (const float*)d_in[16];
  const float* lcb    = (const float*)d_in[17];
  const float* proj_w = (const float*)d_in[18];
  const float* proj_b = (const float*)d_in[19];
  float* outp = (float*)d_out;

  char* ws = (char*)d_ws;
  unsigned short* bufA  = (unsigned short*)(ws);             // lepe-lin bf16
  unsigned short* bufB  = (unsigned short*)(ws + 18874368);  // lepe bf16
  unsigned short* xb    = (unsigned short*)(ws + 37748736);  // x bf16 -> attn out bf16
  unsigned short* Qb    = (unsigned short*)(ws + 47185920);
  unsigned short* wb    = (unsigned short*)(ws + 56623104);
  unsigned short* seqb1 = (unsigned short*)(ws + 59244544);
  unsigned short* seqb2 = (unsigned short*)(ws + 62128128);
  unsigned short* kv1b  = (unsigned short*)(ws + 65011712);
  unsigned short* kv2b  = (unsigned short*)(ws + 67895296);
  unsigned short* Kf    = (unsigned short*)(ws + 70778880);
  unsigned short* Vf    = (unsigned short*)(ws + 73662464);
  int*            idx1  = (int*)(ws + 76546048);
  int*            idx2  = (int*)(ws + 76582912);

  unsigned short* wb_lepe = wb;
  unsigned short* wb_q    = wb + 262144;
  unsigned short* wb_kv1  = wb + 524288;
  unsigned short* wb_kv2  = wb + 786432;
  unsigned short* wb_proj = wb + 1048576;

  dim3 blk(256);

  // L1: argsorts + weight/x pack
  pack_sort<<<dim3(SORTB + PACKB), blk, 0, stream>>>(
      lepe_w, q_w, kv1_w, kv2_w, proj_w, x, wb, xb, mask1, mask2, idx1, idx2);

  // L2: lepe GEMM + q GEMM + pool (pool hides under the GEMM blocks)
  {
    GCfg gl = { xb, wb_lepe, lepe_b, (void*)bufA, 1.f, 1, 72 };
    GCfg gq = { xb, wb_q, q_b, (void*)Qb, 0.18033688011112042f, 1, 72 };
    pool_gemm<<<dim3(576 + 2 * B_ * LKP_), blk, 0, stream>>>(
        gl, gq, ctx, idx1, idx2, f1_w, f1_b, f2_w, f2_b, seqb1, seqb2);
  }

  // L3: kv1 + kv2 GEMMs + dwconv (mutually independent)
  {
    GCfg g1 = { seqb1, wb_kv1, kv1_b, (void*)kv1b, 1.f, 1, 22 };
    GCfg g2 = { seqb2, wb_kv2, kv2_b, (void*)kv2b, 1.f, 1, 22 };
    gconv<<<dim3(176 + 384), blk, 0, stream>>>(g1, g2, bufA, lcw, lcb, bufB);
  }

  // L4: fragment-major K/V pack
  kvpack<<<dim3(32 * 11), blk, 0, stream>>>(kv1b, kv2b, Kf, Vf);

  // L5: attention (fixed-max, v_exp_f32)
  attn_kernel<<<dim3(B_ * NH_ * (N_ / 64)), blk, 0, stream>>>(Qb, Kf, Vf, bufB, xb);

  // L6: final projection -> d_out fp32
  {
    GCfg gp = { xb, wb_proj, proj_b, (void*)outp, 1.f, 0, 72 };
    gemm1<<<dim3(288), blk, 0, stream>>>(gp);
  }
}

// Round 16
// 148.064 us; speedup vs baseline: 1.0628x; 1.0628x over previous
//
#include <hip/hip_runtime.h>
#include <hip/hip_bf16.h>
#include <math.h>

#define B_    4
#define H_    48
#define W_    48
#define N_    2304
#define C_    512
#define NH_   8
#define HD_   64
#define LKV_  684
#define LKP_  704      // padded kv length (11 * 64)

typedef __attribute__((ext_vector_type(8))) short short8;
typedef __attribute__((ext_vector_type(8))) unsigned short ushort8;
typedef __attribute__((ext_vector_type(4))) float f32x4;

#define MFMA16(a, b, c) __builtin_amdgcn_mfma_f32_16x16x32_bf16(a, b, c, 0, 0, 0)

__device__ __forceinline__ unsigned short f2bf(float f) {
  __hip_bfloat16 h = __float2bfloat16(f);
  return *reinterpret_cast<unsigned short*>(&h);
}
__device__ __forceinline__ float bf2f(unsigned short u) {
  unsigned int x = ((unsigned int)u) << 16;
  return *reinterpret_cast<float*>(&x);
}
__device__ __forceinline__ unsigned int cvtpk(float lo, float hi) {
  unsigned int r;
  asm("v_cvt_pk_bf16_f32 %0, %1, %2" : "=v"(r) : "v"(lo), "v"(hi));
  return r;
}
__device__ __forceinline__ float fexp2(float x) {   // raw v_exp_f32: 2^x
  float r;
  asm("v_exp_f32 %0, %1" : "=v"(r) : "v"(x));
  return r;
}
__device__ __forceinline__ void gld16(const unsigned short* g, unsigned short* l) {
  __builtin_amdgcn_global_load_lds(
      (const __attribute__((address_space(1))) void*)g,
      (__attribute__((address_space(3))) void*)l, 16, 0, 0);
}

#define SORTB 288    // argsort blocks (first in grid: long-pole overlap)
#define PACKB 1472   // 6,029,312 floats / (256 thr * 16 floats)

// ---------------- fused: both argsorts (blocks 0..287) + bf16 pack of
// 5 weights + x at 16 floats/thread (blocks 288..1759)
__global__ __launch_bounds__(256) void pack_sort(
    const float* __restrict__ lepe_w, const float* __restrict__ q_w,
    const float* __restrict__ kv1_w, const float* __restrict__ kv2_w,
    const float* __restrict__ proj_w, const float* __restrict__ x,
    unsigned short* __restrict__ wb, unsigned short* __restrict__ xb,
    const float* __restrict__ m1, const float* __restrict__ m2,
    int* __restrict__ i1, int* __restrict__ i2)
{
  __shared__ float key[N_];
  if (blockIdx.x >= SORTB) {
    int i = ((blockIdx.x - SORTB) * 256 + threadIdx.x) * 16;
    const float* s; unsigned short* d; int rel;
    if      (i < 262144)  { s = lepe_w; d = wb;           rel = i; }
    else if (i < 524288)  { s = q_w;    d = wb + 262144;  rel = i - 262144; }
    else if (i < 786432)  { s = kv1_w;  d = wb + 524288;  rel = i - 524288; }
    else if (i < 1048576) { s = kv2_w;  d = wb + 786432;  rel = i - 786432; }
    else if (i < 1310720) { s = proj_w; d = wb + 1048576; rel = i - 1048576; }
    else                  { s = x;      d = xb;           rel = i - 1310720; }
    const float4* sp = (const float4*)(s + rel);
    float4 v0 = sp[0], v1 = sp[1], v2 = sp[2], v3 = sp[3];
    ushort8 o0, o1;
    o0[0] = f2bf(v0.x); o0[1] = f2bf(v0.y); o0[2] = f2bf(v0.z); o0[3] = f2bf(v0.w);
    o0[4] = f2bf(v1.x); o0[5] = f2bf(v1.y); o0[6] = f2bf(v1.z); o0[7] = f2bf(v1.w);
    o1[0] = f2bf(v2.x); o1[1] = f2bf(v2.y); o1[2] = f2bf(v2.z); o1[3] = f2bf(v2.w);
    o1[4] = f2bf(v3.x); o1[5] = f2bf(v3.y); o1[6] = f2bf(v3.z); o1[7] = f2bf(v3.w);
    *(ushort8*)(d + rel)     = o0;
    *(ushort8*)(d + rel + 8) = o1;
    return;
  }
  const int blk = blockIdx.x;
  const int row = blk / 36, chunk = blk % 36;
  const float* m = (row < 4) ? (m1 + (size_t)row * N_) : (m2 + (size_t)(row - 4) * N_);
  int* out = (row < 4) ? (i1 + (size_t)row * N_) : (i2 + (size_t)(row - 4) * N_);
  for (int i = threadIdx.x; i < N_ / 4; i += 256)
    ((float4*)key)[i] = ((const float4*)m)[i];
  __syncthreads();
  const int e = chunk * 64 + (threadIdx.x >> 2);
  const int sl = threadIdx.x & 3;
  const float ki = key[e];
  int rank = 0;
  #pragma unroll 4
  for (int t = 0; t < N_ / 16; ++t) {
    int jb = sl * 4 + t * 16;
    float4 kv = *(const float4*)&key[jb];
    rank += (kv.x < ki) || (kv.x == ki && jb     < e);
    rank += (kv.y < ki) || (kv.y == ki && jb + 1 < e);
    rank += (kv.z < ki) || (kv.z == ki && jb + 2 < e);
    rank += (kv.w < ki) || (kv.w == ki && jb + 3 < e);
  }
  rank += __shfl_xor(rank, 1);
  rank += __shfl_xor(rank, 2);
  if (sl == 0) out[rank] = e;
}

// ---------------- 4-config bf16 MFMA GEMM (NT), global_load_lds staging.
struct GQuad {
  const unsigned short *A[4], *Bw[4];
  const float *bias[4];
  void *out[4];
  float sc[4];
  int bf[4];
  int nx[4];
  int cum[3];
};

__global__ __launch_bounds__(256) void gemm4(GQuad q, int K, int Nn)
{
  int id = blockIdx.x, cfg;
  if      (id < q.cum[0]) { cfg = 0; }
  else if (id < q.cum[1]) { cfg = 1; id -= q.cum[0]; }
  else if (id < q.cum[2]) { cfg = 2; id -= q.cum[1]; }
  else                    { cfg = 3; id -= q.cum[2]; }
  const int bx = id % q.nx[cfg], by = id / q.nx[cfg];

  const unsigned short* A  = q.A[cfg];
  const unsigned short* Bw = q.Bw[cfg];
  const float* bias        = q.bias[cfg];
  void* out                = q.out[cfg];
  const int out_bf16       = q.bf[cfg];
  const float oscale       = q.sc[cfg];

  __shared__ unsigned short Abuf[128 * 32];
  __shared__ unsigned short Bbuf[128 * 32];
  const int tid = threadIdx.x;
  const int l = tid & 63, w = tid >> 6;
  const int wm = w >> 1, wn = w & 1;
  const int lo16 = l & 15, hi = l >> 4;
  const int row0 = bx * 128, col0 = by * 128;
  const int srow = tid >> 2, scol = (tid & 3) * 8;

  const unsigned short* Asrc = A + (size_t)(row0 + srow) * K + scol;
  const unsigned short* Bsrc = Bw + (size_t)(col0 + srow) * K + scol;

  f32x4 acc[4][4];
  #pragma unroll
  for (int m = 0; m < 4; ++m)
    #pragma unroll
    for (int n = 0; n < 4; ++n)
      #pragma unroll
      for (int r = 0; r < 4; ++r) acc[m][n][r] = 0.f;

  for (int k0 = 0; k0 < K; k0 += 32) {
    __syncthreads();
    gld16(Asrc + k0,                   &Abuf[tid * 8]);
    gld16(Asrc + (size_t)64 * K + k0,  &Abuf[2048 + tid * 8]);
    gld16(Bsrc + k0,                   &Bbuf[tid * 8]);
    gld16(Bsrc + (size_t)64 * K + k0,  &Bbuf[2048 + tid * 8]);
    __syncthreads();
    short8 af[4], bf[4];
    #pragma unroll
    for (int m = 0; m < 4; ++m)
      af[m] = *(const short8*)&Abuf[(wm * 64 + m * 16 + lo16) * 32 + hi * 8];
    #pragma unroll
    for (int n = 0; n < 4; ++n)
      bf[n] = *(const short8*)&Bbuf[(wn * 64 + n * 16 + lo16) * 32 + hi * 8];
    #pragma unroll
    for (int m = 0; m < 4; ++m)
      #pragma unroll
      for (int n = 0; n < 4; ++n)
        acc[m][n] = MFMA16(af[m], bf[n], acc[m][n]);
  }

  #pragma unroll
  for (int m = 0; m < 4; ++m) {
    #pragma unroll
    for (int n = 0; n < 4; ++n) {
      int gcol = col0 + wn * 64 + n * 16 + lo16;
      #pragma unroll
      for (int r = 0; r < 4; ++r) {
        int grow = row0 + wm * 64 + m * 16 + hi * 4 + r;
        float v = acc[m][n][r] + bias[gcol];
        if (out_bf16)
          ((unsigned short*)out)[(size_t)grow * Nn + gcol] = f2bf(v * oscale);
        else
          ((float*)out)[(size_t)grow * Nn + gcol] = v;
      }
    }
  }
}

// ---------------- merged: kvpack (blocks 0..351) + dwconv (blocks 352..735)
__global__ __launch_bounds__(256) void packconv(
    const unsigned short* __restrict__ kv1, const unsigned short* __restrict__ kv2,
    unsigned short* __restrict__ Kf, unsigned short* __restrict__ Vf,
    const unsigned short* __restrict__ lin, const float* __restrict__ cw,
    const float* __restrict__ cb, unsigned short* __restrict__ outp)
{
  __shared__ unsigned short Vt[64][72];
  const int tid = threadIdx.x;
  if (blockIdx.x < 352) {
    const int kb = blockIdx.x;
    const int bh = kb / 11, t = kb % 11;
    const int h = bh & 7, b = bh >> 3;
    const unsigned short* src = (h < 4) ? kv1 : kv2;
    const int hcol = (h & 3) * 64;

    #pragma unroll
    for (int pass = 0; pass < 2; ++pass) {
      int r = pass * 32 + (tid >> 3);
      int cc = (tid & 7) * 8;
      int l = t * 64 + r;
      uint4 v = make_uint4(0, 0, 0, 0);
      if (l < LKV_)
        v = *(const uint4*)&src[(size_t)(b * LKP_ + l) * C_ + 256 + hcol + cc];
      *(uint4*)&Vt[r][cc] = v;
    }
    __syncthreads();

    #pragma unroll
    for (int pass = 0; pass < 2; ++pass) {
      int o = pass * 256 + tid;
      int lane = o & 63, ns = o >> 6;
      int frag = ns >> 1, s = ns & 1;
      int lo16 = lane & 15, hi8 = (lane >> 4) * 8;
      size_t oidx = ((size_t)kb * 8 + ns) * 512 + lane * 8;
      {
        int l = t * 64 + frag * 16 + lo16;
        uint4 val = make_uint4(0, 0, 0, 0);
        if (l < LKV_)
          val = *(const uint4*)&src[(size_t)(b * LKP_ + l) * C_ + hcol + s * 32 + hi8];
        *(uint4*)&Kf[oidx] = val;
      }
      {
        unsigned short tmp[8];
        #pragma unroll
        for (int j = 0; j < 8; ++j)
          tmp[j] = Vt[s * 32 + hi8 + j][frag * 16 + lo16];
        *(uint4*)&Vf[oidx] = *(uint4*)tmp;
      }
    }
    return;
  }
  // ---- dwconv
  const int cg = tid & 63;
  const int wslot = (blockIdx.x - 352) * 4 + (tid >> 6);
  const int nslots = (gridDim.x - 352) * 4;

  float wf[72];
  const float* wsrc = cw + cg * 72;
  #pragma unroll
  for (int i = 0; i < 18; ++i)
    *(float4*)&wf[i * 4] = *(const float4*)(wsrc + i * 4);
  float bias[8];
  *(float4*)&bias[0] = *(const float4*)(cb + cg * 8);
  *(float4*)&bias[4] = *(const float4*)(cb + cg * 8 + 4);

  for (int pos = wslot; pos < B_ * N_; pos += nslots) {
    int wv = pos % W_;
    int r  = pos / W_;
    int hv = r % H_;
    int b  = r / H_;
    float acc[8];
    #pragma unroll
    for (int j = 0; j < 8; ++j) acc[j] = bias[j];
    #pragma unroll
    for (int dy = 0; dy < 3; ++dy) {
      int hh = hv + dy - 1;
      if (hh < 0 || hh >= H_) continue;
      #pragma unroll
      for (int dx = 0; dx < 3; ++dx) {
        int ww = wv + dx - 1;
        if (ww < 0 || ww >= W_) continue;
        ushort8 v = *(const ushort8*)(lin + ((((size_t)b * H_ + hh) * W_ + ww) * 64 + cg) * 8);
        #pragma unroll
        for (int j = 0; j < 8; ++j)
          acc[j] += wf[j * 9 + dy * 3 + dx] * bf2f(v[j]);
      }
    }
    ushort8 ov;
    #pragma unroll
    for (int j = 0; j < 8; ++j) ov[j] = f2bf(acc[j]);
    *(ushort8*)(outp + ((size_t)pos * 64 + cg) * 8) = ov;
  }
}

// ---------------- pooled sequences (both orderings in one launch)
__global__ __launch_bounds__(256) void pool_kernel(
    const float* __restrict__ ctx,
    const int* __restrict__ idx1, const int* __restrict__ idx2,
    const float* __restrict__ f1w, const float* __restrict__ f1b,
    const float* __restrict__ f2w, const float* __restrict__ f2b_,
    unsigned short* __restrict__ seqb1, unsigned short* __restrict__ seqb2)
{
  int bl = blockIdx.x;
  const int transposed = bl >= B_ * LKP_;
  if (transposed) bl -= B_ * LKP_;
  const int* idx = transposed ? idx2 : idx1;
  unsigned short* seqb = transposed ? seqb2 : seqb1;
  int b = bl / LKP_, l = bl % LKP_;
  unsigned short* dst = seqb + ((size_t)b * LKP_ + l) * C_;
  int c0 = threadIdx.x, c1 = threadIdx.x + 256;
  if (l >= LKV_) { dst[c0] = 0; dst[c1] = 0; return; }
  const int* id = idx + (size_t)b * N_;
  int j0, cnt;
  const float* fw; float fb;
  if (l < 12)       { j0 = l * 48;              cnt = 48; fw = f1w; fb = f1b[0]; }
  else if (l < 108) { j0 = 576 + (l - 12) * 12; cnt = 12; fw = f2w; fb = f2b_[0]; }
  else              { j0 = 1728 + (l - 108);    cnt = 1;  fw = nullptr; fb = 0.f; }
  const float* cb = ctx + (size_t)b * N_ * C_;
  float a0 = fb, a1 = fb;
  int r = 0;
  for (; r + 4 <= cnt; r += 4) {
    int4 nv = *(const int4*)(id + j0 + r);
    int n0 = nv.x, n1 = nv.y, n2 = nv.z, n3 = nv.w;
    if (transposed) {
      n0 = (n0 % 48) * 48 + n0 / 48; n1 = (n1 % 48) * 48 + n1 / 48;
      n2 = (n2 % 48) * 48 + n2 / 48; n3 = (n3 % 48) * 48 + n3 / 48;
    }
    const float* s0 = cb + (size_t)n0 * C_;
    const float* s1 = cb + (size_t)n1 * C_;
    const float* s2 = cb + (size_t)n2 * C_;
    const float* s3 = cb + (size_t)n3 * C_;
    float w0 = fw[r], w1 = fw[r+1], w2 = fw[r+2], w3 = fw[r+3];
    a0 += w0 * s0[c0] + w1 * s1[c0] + w2 * s2[c0] + w3 * s3[c0];
    a1 += w0 * s0[c1] + w1 * s1[c1] + w2 * s2[c1] + w3 * s3[c1];
  }
  for (; r < cnt; ++r) {
    int n = id[j0 + r];
    if (transposed) n = (n % 48) * 48 + n / 48;
    const float* src = cb + (size_t)n * C_;
    float wr = fw ? fw[r] : 1.f;
    a0 += wr * src[c0];
    a1 += wr * src[c1];
  }
  dst[c0] = f2bf(a0);
  dst[c1] = f2bf(a1);
}

// ---------------- fused flash attention: 16 q-rows/wave, 4 waves/block,
// swapped QK^T, FIXED-max softmax (M=0, raw v_exp_f32 — scores |s|<~2 so
// exp2(s) can't overflow; softmax renormalizes), cvt_pk P-pack, bf16 lepe
// epilogue.
__global__ __launch_bounds__(256) void attn_kernel(
    const unsigned short* __restrict__ Qb, const unsigned short* __restrict__ Kf,
    const unsigned short* __restrict__ Vf, const unsigned short* __restrict__ lepe,
    unsigned short* __restrict__ outb)
{
  __shared__ unsigned short P[4][16][72];
  const int tid = threadIdx.x;
  const int l = tid & 63, wv = tid >> 6;
  const int lo16 = l & 15, hi = l >> 4;
  const int qt64 = blockIdx.x % (N_ / 64);
  const int bh = blockIdx.x / (N_ / 64);
  const int h = bh & 7, b = bh >> 3;
  const int qrow0 = qt64 * 64 + wv * 16;

  const unsigned short* qptr = Qb + ((size_t)b * N_ + qrow0 + lo16) * C_ + h * 64;
  short8 qf0 = *(const short8*)(qptr + hi * 8);
  short8 qf1 = *(const short8*)(qptr + 32 + hi * 8);

  const unsigned short* kbase = Kf + (size_t)bh * 11 * 4096 + (size_t)l * 8;
  const unsigned short* vbase = Vf + (size_t)bh * 11 * 4096 + (size_t)l * 8;

  float lsum = 0.f;
  f32x4 o[4];
  #pragma unroll
  for (int df = 0; df < 4; ++df)
    #pragma unroll
    for (int r = 0; r < 4; ++r) o[df][r] = 0.f;

  short8 ka0[4], ka1[4], kn0[4], kn1[4];
  #pragma unroll
  for (int n = 0; n < 4; ++n) {
    ka0[n] = *(const short8*)(kbase + (size_t)(n * 2 + 0) * 512);
    ka1[n] = *(const short8*)(kbase + (size_t)(n * 2 + 1) * 512);
  }

  for (int t = 0; t < 11; ++t) {
    short8 vf0[4], vf1[4];
    #pragma unroll
    for (int i = 0; i < 4; ++i) {
      vf0[i] = *(const short8*)(vbase + (size_t)(t * 8 + i * 2 + 0) * 512);
      vf1[i] = *(const short8*)(vbase + (size_t)(t * 8 + i * 2 + 1) * 512);
    }
    if (t < 10) {
      #pragma unroll
      for (int n = 0; n < 4; ++n) {
        kn0[n] = *(const short8*)(kbase + (size_t)((t + 1) * 8 + n * 2 + 0) * 512);
        kn1[n] = *(const short8*)(kbase + (size_t)((t + 1) * 8 + n * 2 + 1) * 512);
      }
    }
    const f32x4 z = {0.f, 0.f, 0.f, 0.f};
    f32x4 s[4];
    #pragma unroll
    for (int n = 0; n < 4; ++n) {
      s[n] = MFMA16(ka0[n], qf0, z);
      s[n] = MFMA16(ka1[n], qf1, s[n]);
    }
    if (t == 10) {
      #pragma unroll
      for (int n = 0; n < 4; ++n)
        #pragma unroll
        for (int r = 0; r < 4; ++r)
          if (n * 16 + hi * 4 + r >= LKV_ - 640) s[n][r] = -1e30f;
    }
    // fixed-max exp2 (M=0): purely per-lane, 1 transcendental per score
    float psl = 0.f;
    #pragma unroll
    for (int n = 0; n < 4; ++n) {
      #pragma unroll
      for (int rp = 0; rp < 2; ++rp) {
        float e0 = fexp2(s[n][2 * rp]);
        float e1 = fexp2(s[n][2 * rp + 1]);
        psl += e0 + e1;
        *(unsigned int*)&P[wv][lo16][n * 16 + hi * 4 + 2 * rp] = cvtpk(e0, e1);
      }
    }
    lsum += psl;
    short8 pa0 = *(const short8*)&P[wv][lo16][hi * 8];
    short8 pa1 = *(const short8*)&P[wv][lo16][32 + hi * 8];
    #pragma unroll
    for (int df = 0; df < 4; ++df) {
      o[df] = MFMA16(pa0, vf0[df], o[df]);
      o[df] = MFMA16(pa1, vf1[df], o[df]);
    }
    #pragma unroll
    for (int n = 0; n < 4; ++n) { ka0[n] = kn0[n]; ka1[n] = kn1[n]; }
  }

  lsum += __shfl_xor(lsum, 16);
  lsum += __shfl_xor(lsum, 32);
  float rr[4];
  #pragma unroll
  for (int r = 0; r < 4; ++r) rr[r] = 1.f / __shfl(lsum, hi * 4 + r);
  #pragma unroll
  for (int df = 0; df < 4; ++df)
    #pragma unroll
    for (int r = 0; r < 4; ++r) {
      size_t off = ((size_t)b * N_ + qrow0 + hi * 4 + r) * C_ + h * 64 + df * 16 + lo16;
      outb[off] = f2bf(o[df][r] * rr[r] + bf2f(lepe[off]));
    }
}

extern "C" void kernel_launch(void* const* d_in, const int* in_sizes, int n_in,
                              void* d_out, int out_size, void* d_ws, size_t ws_size,
                              hipStream_t stream)
{
  const float* x      = (const float*)d_in[0];
  const float* ctx    = (const float*)d_in[1];
  const float* mask1  = (const float*)d_in[2];
  const float* mask2  = (const float*)d_in[3];
  const float* q_w    = (const float*)d_in[4];
  const float* q_b    = (const float*)d_in[5];
  const float* kv1_w  = (const float*)d_in[6];
  const float* kv1_b  = (const float*)d_in[7];
  const float* kv2_w  = (const float*)d_in[8];
  const float* kv2_b  = (const float*)d_in[9];
  const float* f1_w   = (const float*)d_in[10];
  const float* f1_b   = (const float*)d_in[11];
  const float* f2_w   = (const float*)d_in[12];
  const float* f2_b   = (const float*)d_in[13];
  const float* lepe_w = (const float*)d_in[14];
  const float* lepe_b = (const float*)d_in[15];
  const float* lcw    = (const float*)d_in[16];
  const float* lcb    = (const float*)d_in[17];
  const float* proj_w = (const float*)d_in[18];
  const float* proj_b = (const float*)d_in[19];
  float* outp = (float*)d_out;

  char* ws = (char*)d_ws;
  unsigned short* bufA  = (unsigned short*)(ws);             // lepe-lin bf16
  unsigned short* bufB  = (unsigned short*)(ws + 18874368);  // lepe bf16
  unsigned short* xb    = (unsigned short*)(ws + 37748736);  // x bf16 -> attn out bf16
  unsigned short* Qb    = (unsigned short*)(ws + 47185920);
  unsigned short* wb    = (unsigned short*)(ws + 56623104);
  unsigned short* seqb1 = (unsigned short*)(ws + 59244544);
  unsigned short* seqb2 = (unsigned short*)(ws + 62128128);
  unsigned short* kv1b  = (unsigned short*)(ws + 65011712);
  unsigned short* kv2b  = (unsigned short*)(ws + 67895296);
  unsigned short* Kf    = (unsigned short*)(ws + 70778880);
  unsigned short* Vf    = (unsigned short*)(ws + 73662464);
  int*            idx1  = (int*)(ws + 76546048);
  int*            idx2  = (int*)(ws + 76582912);

  unsigned short* wb_lepe = wb;
  unsigned short* wb_q    = wb + 262144;
  unsigned short* wb_kv1  = wb + 524288;
  unsigned short* wb_kv2  = wb + 786432;
  unsigned short* wb_proj = wb + 1048576;

  dim3 blk(256);

  // argsorts first (long-pole blocks overlap the pack), then 16-float/thread pack
  pack_sort<<<dim3(SORTB + PACKB), blk, 0, stream>>>(
      lepe_w, q_w, kv1_w, kv2_w, proj_w, x, wb, xb, mask1, mask2, idx1, idx2);

  pool_kernel<<<dim3(2 * B_ * LKP_), blk, 0, stream>>>(
      ctx, idx1, idx2, f1_w, f1_b, f2_w, f2_b, seqb1, seqb2);

  // all four projections (kv1, kv2, lepe, q) in ONE launch: 88+88+288+288 blocks
  {
    GQuad q;
    q.A[0] = seqb1; q.Bw[0] = wb_kv1;  q.bias[0] = kv1_b;  q.out[0] = (void*)kv1b;
    q.A[1] = seqb2; q.Bw[1] = wb_kv2;  q.bias[1] = kv2_b;  q.out[1] = (void*)kv2b;
    q.A[2] = xb;    q.Bw[2] = wb_lepe; q.bias[2] = lepe_b; q.out[2] = (void*)bufA;
    q.A[3] = xb;    q.Bw[3] = wb_q;    q.bias[3] = q_b;    q.out[3] = (void*)Qb;
    q.sc[0] = 1.f; q.sc[1] = 1.f; q.sc[2] = 1.f; q.sc[3] = 0.18033688011112042f;
    q.bf[0] = 1; q.bf[1] = 1; q.bf[2] = 1; q.bf[3] = 1;
    q.nx[0] = 22; q.nx[1] = 22; q.nx[2] = 72; q.nx[3] = 72;
    q.cum[0] = 88; q.cum[1] = 176; q.cum[2] = 464;
    gemm4<<<dim3(752), blk, 0, stream>>>(q, C_, C_);
  }

  // kvpack (352 blocks) + dwconv (384 blocks) in one launch
  packconv<<<dim3(736), blk, 0, stream>>>(kv1b, kv2b, Kf, Vf, bufA, lcw, lcb, bufB);

  // 16-row/wave, 4 waves/block attention (fixed-max M=0, v_exp_f32)
  attn_kernel<<<dim3(B_ * NH_ * (N_ / 64)), blk, 0, stream>>>(Qb, Kf, Vf, bufB, xb);

  // final projection -> d_out fp32 (single-config use of gemm4)
  {
    GQuad q;
    q.A[0] = xb; q.Bw[0] = wb_proj; q.bias[0] = proj_b; q.out[0] = (void*)outp;
    q.A[1] = q.A[2] = q.A[3] = xb;
    q.Bw[1] = q.Bw[2] = q.Bw[3] = wb_proj;
    q.bias[1] = q.bias[2] = q.bias[3] = proj_b;
    q.out[1] = q.out[2] = q.out[3] = (void*)outp;
    q.sc[0] = q.sc[1] = q.sc[2] = q.sc[3] = 1.f;
    q.bf[0] = q.bf[1] = q.bf[2] = q.bf[3] = 0;
    q.nx[0] = q.nx[1] = q.nx[2] = q.nx[3] = 72;
    q.cum[0] = q.cum[1] = q.cum[2] = 288;
    gemm4<<<dim3(288), blk, 0, stream>>>(q, C_, C_);
  }
}